// Round 1
// baseline (6437.855 us; speedup 1.0000x reference)
//
#include <hip/hip_runtime.h>
#include <hip/hip_cooperative_groups.h>

namespace cg = cooperative_groups;

#define SEQ   32
#define HH    128
#define WW    128
#define CINC  8
#define COUTC 8
#define NG    32      // 4*Cout gates
#define ICH   16      // Cin+Cout
#define TAPS  9
#define ROWS  4       // 2 output rows + halo
#define COLS  130     // 128 + halo

typedef _Float16 half8 __attribute__((ext_vector_type(8)));
typedef float floatx16 __attribute__((ext_vector_type(16)));

__device__ __forceinline__ float fast_rcp(float x) { return __builtin_amdgcn_rcpf(x); }
__device__ __forceinline__ float sigmoidf_(float x) {
    return fast_rcp(1.0f + __expf(-x));
}
__device__ __forceinline__ float tanhf_(float x) {
    float e = __expf(-2.0f * x);
    return (1.0f - e) * fast_rcp(1.0f + e);
}

// Wc[g][ic][ky][kx] fp32 -> Wf[tap][gate][ch_half][8ch] f16 (A-operand fragments)
__global__ void prep_weights(const float* __restrict__ Wc, _Float16* __restrict__ Wf) {
    int i = blockIdx.x * 256 + threadIdx.x;
    if (i >= TAPS * NG * ICH) return;
    int tap = i / (NG * ICH);
    int r   = i % (NG * ICH);
    int g   = r >> 4;
    int ch  = r & 15;
    int half = ch >> 3, c8 = ch & 7;
    int ky = tap / 3, kx = tap % 3;
    float w = Wc[g * (ICH * 9) + ch * 9 + ky * 3 + kx];
    Wf[((tap * NG + g) * 2 + half) * 8 + c8] = (_Float16)w;
}

// ---------------------------------------------------------------------------
// Fused persistent kernel: all 32 timesteps in one cooperative launch.
// Block mapping identical to step_kernel (b = blk>>6, y0 = (blk&63)*2) but
// now FIXED across time, so the c-state lives in 8 VGPRs per lane and never
// touches global memory. One grid.sync() per step orders h(t-1) writes
// before the t-staging reads.
// ---------------------------------------------------------------------------
__global__ __launch_bounds__(256, 4) void lstm_fused(
    const float* __restrict__ X,      // (B, Cin, S, H, W)
    const _Float16* __restrict__ Wf,  // (9, 32, 2, 8)
    const float* __restrict__ bc,     // (32,)
    float* __restrict__ out)          // (B, Cout, S, H, W) -- also h history
{
    __shared__ __align__(16) _Float16 ldsH[2 * ROWS * COLS * 8];
    __shared__ __align__(16) _Float16 ldsL[2 * ROWS * COLS * 8];

    const int tid = threadIdx.x;
    const int b   = blockIdx.x >> 6;
    const int y0  = (blockIdx.x & 63) * 2;

    const int lane = tid & 63;
    const int w    = tid >> 6;       // wave 0..3
    const int lg   = lane & 31;      // A: gate row; B: pixel col
    const int lh   = lane >> 5;      // ch half / k-group

    // weight A-fragments: loaded ONCE for all 32 steps (36 VGPRs)
    half8 wfrag[TAPS];
#pragma unroll
    for (int tap = 0; tap < TAPS; ++tap)
        wfrag[tap] = *(const half8*)&Wf[((tap * NG + lg) * 2 + lh) * 8];

    // c-state: loop-carried in registers, zero-initialized (c0 = 0)
    float creg[8];
#pragma unroll
    for (int r = 0; r < 8; ++r) creg[r] = 0.0f;

    const int ry = w >> 1;           // 0..1
    const int x0 = (w & 1) * 64;
    const int y  = y0 + ry;

    cg::grid_group grid = cg::this_grid();

    for (int t = 0; t < SEQ; ++t) {
        // ---- stage x(t) + h(t-1) as f16 hi/lo, layout [half][row][col][8ch] ----
        for (int idx = tid; idx < 2 * ROWS * COLS; idx += 256) {
            int col  = idx % COLS;
            int tmp  = idx / COLS;     // 0..7
            int half = tmp >> 2;
            int row  = tmp & 3;
            int gy = y0 + row - 1;
            int gx = col - 1;
            bool inb = ((unsigned)gy < HH) && ((unsigned)gx < WW);
            float v[8];
#pragma unroll
            for (int j = 0; j < 8; ++j) {
                int ch = half * 8 + j;
                float val = 0.0f;
                if (inb) {
                    if (ch < CINC)
                        val = X[(((size_t)(b * CINC + ch) * SEQ + t) * HH + gy) * WW + gx];
                    else if (t > 0)
                        val = out[(((size_t)(b * COUTC + (ch - 8)) * SEQ + (t - 1)) * HH + gy) * WW + gx];
                }
                v[j] = val;
            }
            union { half8 h; float4 f; } uh, ul;
#pragma unroll
            for (int j = 0; j < 8; ++j) {
                _Float16 hi = (_Float16)v[j];
                uh.h[j] = hi;
                ul.h[j] = (_Float16)(v[j] - (float)hi);
            }
            *(float4*)&ldsH[(size_t)idx * 8] = uh.f;
            *(float4*)&ldsL[(size_t)idx * 8] = ul.f;
        }
        __syncthreads();

        // ---- MFMA: wave covers row ry, cols x0..x0+63 (2 N-tiles) ----
        floatx16 acc0, acc1;
#pragma unroll
        for (int r = 0; r < 16; ++r) { acc0[r] = 0.0f; acc1[r] = 0.0f; }

#pragma unroll
        for (int tap = 0; tap < TAPS; ++tap) {
            int ky = tap / 3, kx = tap % 3;
            int row = ry + ky;
            int base0 = ((lh * ROWS + row) * COLS + (x0 + lg + kx)) * 8;
            int base1 = base0 + 32 * 8;
            half8 bh0 = *(const half8*)&ldsH[base0];
            half8 bl0 = *(const half8*)&ldsL[base0];
            half8 bh1 = *(const half8*)&ldsH[base1];
            half8 bl1 = *(const half8*)&ldsL[base1];
            acc0 = __builtin_amdgcn_mfma_f32_32x32x16_f16(wfrag[tap], bh0, acc0, 0, 0, 0);
            acc1 = __builtin_amdgcn_mfma_f32_32x32x16_f16(wfrag[tap], bh1, acc1, 0, 0, 0);
            acc0 = __builtin_amdgcn_mfma_f32_32x32x16_f16(wfrag[tap], bl0, acc0, 0, 0, 0);
            acc1 = __builtin_amdgcn_mfma_f32_32x32x16_f16(wfrag[tap], bl1, acc1, 0, 0, 0);
        }

        // ---- epilogue: lane holds gates {oc, oc+8, oc+16, oc+24}, oc = r + 4*lh ----
#pragma unroll
        for (int tl = 0; tl < 2; ++tl) {
            floatx16 A = tl ? acc1 : acc0;
            int px = x0 + tl * 32 + lg;
#pragma unroll
            for (int r = 0; r < 4; ++r) {
                int oc = r + 4 * lh;
                float zi = A[r]      + bc[oc];
                float zf = A[4 + r]  + bc[oc + 8];
                float zg = A[8 + r]  + bc[oc + 16];
                float zo = A[12 + r] + bc[oc + 24];
                float cp = creg[tl * 4 + r];
                float cn = sigmoidf_(zf) * cp + sigmoidf_(zi) * tanhf_(zg);
                creg[tl * 4 + r] = cn;
                out[(((size_t)(b * COUTC + oc) * SEQ + t) * HH + y) * WW + px]
                    = sigmoidf_(zo) * tanhf_(cn);
            }
        }

        // order h(t) writes before t+1 staging reads (cross-XCD: fence + grid barrier);
        // also serves as the block barrier protecting LDS reuse
        if (t + 1 < SEQ) {
            __threadfence();
            grid.sync();
        }
    }
}

// ---------------------------------------------------------------------------
// Fallback path (proven baseline): one kernel per step, c-state in workspace.
// Used only if the cooperative launch is rejected.
// ---------------------------------------------------------------------------
__global__ __launch_bounds__(256, 4) void step_kernel(
    const float* __restrict__ X,
    const _Float16* __restrict__ Wf,
    const float* __restrict__ bc,
    float* __restrict__ out,
    float* __restrict__ c,
    int t)
{
    __shared__ __align__(16) _Float16 ldsH[2 * ROWS * COLS * 8];
    __shared__ __align__(16) _Float16 ldsL[2 * ROWS * COLS * 8];

    const int tid = threadIdx.x;
    const int b   = blockIdx.x >> 6;
    const int y0  = (blockIdx.x & 63) * 2;

    for (int idx = tid; idx < 2 * ROWS * COLS; idx += 256) {
        int col  = idx % COLS;
        int tmp  = idx / COLS;
        int half = tmp >> 2;
        int row  = tmp & 3;
        int gy = y0 + row - 1;
        int gx = col - 1;
        bool inb = ((unsigned)gy < HH) && ((unsigned)gx < WW);
        float v[8];
#pragma unroll
        for (int j = 0; j < 8; ++j) {
            int ch = half * 8 + j;
            float val = 0.0f;
            if (inb) {
                if (ch < CINC)
                    val = X[(((size_t)(b * CINC + ch) * SEQ + t) * HH + gy) * WW + gx];
                else if (t > 0)
                    val = out[(((size_t)(b * COUTC + (ch - 8)) * SEQ + (t - 1)) * HH + gy) * WW + gx];
            }
            v[j] = val;
        }
        union { half8 h; float4 f; } uh, ul;
#pragma unroll
        for (int j = 0; j < 8; ++j) {
            _Float16 hi = (_Float16)v[j];
            uh.h[j] = hi;
            ul.h[j] = (_Float16)(v[j] - (float)hi);
        }
        *(float4*)&ldsH[(size_t)idx * 8] = uh.f;
        *(float4*)&ldsL[(size_t)idx * 8] = ul.f;
    }

    const int lane = tid & 63;
    const int w    = tid >> 6;
    const int lg   = lane & 31;
    const int lh   = lane >> 5;

    half8 wfrag[TAPS];
#pragma unroll
    for (int tap = 0; tap < TAPS; ++tap)
        wfrag[tap] = *(const half8*)&Wf[((tap * NG + lg) * 2 + lh) * 8];

    __syncthreads();

    const int ry = w >> 1;
    const int x0 = (w & 1) * 64;

    floatx16 acc0, acc1;
#pragma unroll
    for (int r = 0; r < 16; ++r) { acc0[r] = 0.0f; acc1[r] = 0.0f; }

#pragma unroll
    for (int tap = 0; tap < TAPS; ++tap) {
        int ky = tap / 3, kx = tap % 3;
        int row = ry + ky;
        int base0 = ((lh * ROWS + row) * COLS + (x0 + lg + kx)) * 8;
        int base1 = base0 + 32 * 8;
        half8 bh0 = *(const half8*)&ldsH[base0];
        half8 bl0 = *(const half8*)&ldsL[base0];
        half8 bh1 = *(const half8*)&ldsH[base1];
        half8 bl1 = *(const half8*)&ldsL[base1];
        acc0 = __builtin_amdgcn_mfma_f32_32x32x16_f16(wfrag[tap], bh0, acc0, 0, 0, 0);
        acc1 = __builtin_amdgcn_mfma_f32_32x32x16_f16(wfrag[tap], bh1, acc1, 0, 0, 0);
        acc0 = __builtin_amdgcn_mfma_f32_32x32x16_f16(wfrag[tap], bl0, acc0, 0, 0, 0);
        acc1 = __builtin_amdgcn_mfma_f32_32x32x16_f16(wfrag[tap], bl1, acc1, 0, 0, 0);
    }

    const int y = y0 + ry;
#pragma unroll
    for (int tl = 0; tl < 2; ++tl) {
        floatx16 A = tl ? acc1 : acc0;
        int px = x0 + tl * 32 + lg;
#pragma unroll
        for (int r = 0; r < 4; ++r) {
            int oc = r + 4 * lh;
            float zi = A[r]      + bc[oc];
            float zf = A[4 + r]  + bc[oc + 8];
            float zg = A[8 + r]  + bc[oc + 16];
            float zo = A[12 + r] + bc[oc + 24];
            size_t ci = ((size_t)(b * COUTC + oc) * HH + y) * WW + px;
            float cp = (t > 0) ? c[ci] : 0.0f;
            float cn = sigmoidf_(zf) * cp + sigmoidf_(zi) * tanhf_(zg);
            c[ci] = cn;
            out[(((size_t)(b * COUTC + oc) * SEQ + t) * HH + y) * WW + px]
                = sigmoidf_(zo) * tanhf_(cn);
        }
    }
}

extern "C" void kernel_launch(void* const* d_in, const int* in_sizes, int n_in,
                              void* d_out, int out_size, void* d_ws, size_t ws_size,
                              hipStream_t stream) {
    const float* X  = (const float*)d_in[0];
    const float* Wc = (const float*)d_in[1];
    const float* bc = (const float*)d_in[2];
    float* out = (float*)d_out;

    _Float16* Wf = (_Float16*)d_ws;                           // 4608 f16 = 9216 B

    prep_weights<<<(TAPS * NG * ICH + 255) / 256, 256, 0, stream>>>(Wc, Wf);

    void* args[] = { (void*)&X, (void*)&Wf, (void*)&bc, (void*)&out };
    hipError_t err = hipLaunchCooperativeKernel((const void*)lstm_fused,
                                                dim3(16 * 64), dim3(256),
                                                args, 0, stream);
    if (err != hipSuccess) {
        // fallback: proven per-step path with c-state in workspace
        float* c = (float*)((char*)d_ws + 16384);
        for (int t = 0; t < SEQ; ++t) {
            step_kernel<<<16 * 64, 256, 0, stream>>>(X, Wf, bc, out, c, t);
        }
    }
}

// Round 3
// 854.644 us; speedup vs baseline: 7.5328x; 7.5328x over previous
//
#include <hip/hip_runtime.h>

#define SEQ   32
#define HH    128
#define WW    128
#define CINC  8
#define COUTC 8
#define NG    32      // 4*Cout gates
#define ICH   16      // Cin+Cout
#define TAPS  9
#define ROWS  4       // 2 output rows + halo
#define COLS  130     // 128 + halo

typedef _Float16 half8 __attribute__((ext_vector_type(8)));
typedef _Float16 half4 __attribute__((ext_vector_type(4)));
typedef float floatx16 __attribute__((ext_vector_type(16)));

__device__ __forceinline__ float fast_rcp(float x) { return __builtin_amdgcn_rcpf(x); }
__device__ __forceinline__ float sigmoidf_(float x) {
    return fast_rcp(1.0f + __expf(-x));
}
__device__ __forceinline__ float tanhf_(float x) {
    float e = __expf(-2.0f * x);
    return (1.0f - e) * fast_rcp(1.0f + e);
}

// Wc[g][ic][ky][kx] fp32 -> Wf[tap][gate][ch_half][8ch] f16 (A-operand fragments)
// Also zeroes the 1024 progress flags (workspace is poisoned between runs).
__global__ void prep_weights(const float* __restrict__ Wc, _Float16* __restrict__ Wf,
                             unsigned* __restrict__ flags) {
    int i = blockIdx.x * 256 + threadIdx.x;
    if (i < 1024) flags[i] = 0u;
    if (i >= TAPS * NG * ICH) return;
    int tap = i / (NG * ICH);
    int r   = i % (NG * ICH);
    int g   = r >> 4;
    int ch  = r & 15;
    int half = ch >> 3, c8 = ch & 7;
    int ky = tap / 3, kx = tap % 3;
    float w = Wc[g * (ICH * 9) + ch * 9 + ky * 3 + kx];
    Wf[((tap * NG + g) * 2 + half) * 8 + c8] = (_Float16)w;
}

// ---------------------------------------------------------------------------
// Fused persistent kernel, neighbor-flag sync.
//  - flag publish AND poll are atomic RMWs -> always serviced at the
//    coherence point (cross-XCD safe, no fences, no cache invalidates)
//  - ordering: __syncthreads() before publish implies vmcnt(0) drain, so all
//    sc1 out-stores are globally visible before the flag RMW issues
//  - bounded spin (100K polls) turns any residual protocol bug into a
//    wrong-answer failure instead of a hung container
//  - c-state in registers; own h rows handed to next step via LDS; only the
//    2 halo rows are re-read from global (sc1 loads = coherence point)
// ---------------------------------------------------------------------------
__global__ __launch_bounds__(256, 4) void lstm_fused(
    const float* __restrict__ X,      // (B, Cin, S, H, W)
    const _Float16* __restrict__ Wf,  // (9, 32, 2, 8)
    const float* __restrict__ bc,     // (32,)
    float* __restrict__ out,          // (B, Cout, S, H, W) -- also h history
    unsigned* __restrict__ flags)     // (1024,) steps completed per block
{
    __shared__ __align__(16) _Float16 ldsH[2 * ROWS * COLS * 8];
    __shared__ __align__(16) _Float16 ldsL[2 * ROWS * COLS * 8];

    const int tid = threadIdx.x;
    const int blk = blockIdx.x;
    const int b   = blk >> 6;
    const int yb  = blk & 63;
    const int y0  = yb * 2;

    const int lane = tid & 63;
    const int w    = tid >> 6;       // wave 0..3
    const int lg   = lane & 31;      // A: gate row; B: pixel col
    const int lh   = lane >> 5;      // ch half / k-group

    const bool hasUp = (yb > 0);
    const bool hasDn = (yb < 63);

    // weight A-fragments: loaded ONCE for all 32 steps
    half8 wfrag[TAPS];
#pragma unroll
    for (int tap = 0; tap < TAPS; ++tap)
        wfrag[tap] = *(const half8*)&Wf[((tap * NG + lg) * 2 + lh) * 8];

    // biases hoisted
    float bi[4], bf4[4], bg[4], bo[4];
#pragma unroll
    for (int r = 0; r < 4; ++r) {
        int oc = r + 4 * lh;
        bi[r]  = bc[oc];
        bf4[r] = bc[oc + 8];
        bg[r]  = bc[oc + 16];
        bo[r]  = bc[oc + 24];
    }

    // c-state: loop-carried in registers (c0 = 0)
    float creg[8];
#pragma unroll
    for (int r = 0; r < 8; ++r) creg[r] = 0.0f;

    const int ry = w >> 1;           // 0..1
    const int x0 = (w & 1) * 64;
    const int y  = y0 + ry;

    for (int t = 0; t < SEQ; ++t) {
        // ---- wait for row-neighbors to have completed step t-1 ----
        if (t > 0) {
            if (tid == 0 && hasUp) {
                int polls = 0;
                while (__hip_atomic_fetch_add(&flags[blk - 1], 0u, __ATOMIC_RELAXED,
                                              __HIP_MEMORY_SCOPE_AGENT) < (unsigned)t
                       && ++polls < 100000)
                    __builtin_amdgcn_s_sleep(2);
            }
            if (tid == 64 && hasDn) {
                int polls = 0;
                while (__hip_atomic_fetch_add(&flags[blk + 1], 0u, __ATOMIC_RELAXED,
                                              __HIP_MEMORY_SCOPE_AGENT) < (unsigned)t
                       && ++polls < 100000)
                    __builtin_amdgcn_s_sleep(2);
            }
            __syncthreads();
        }

        // ---- stage: X (all rows) + h halo rows 0,3 (rows 1,2 already in LDS) ----
        for (int idx = tid; idx < 2 * ROWS * COLS; idx += 256) {
            int col  = idx % COLS;
            int tmp  = idx / COLS;     // 0..7
            int half = tmp >> 2;
            int row  = tmp & 3;
            if (half == 1 && t > 0 && (row == 1 || row == 2)) continue; // own h in LDS
            int gy = y0 + row - 1;
            int gx = col - 1;
            bool inb = ((unsigned)gy < HH) && ((unsigned)gx < WW);
            float v[8];
#pragma unroll
            for (int j = 0; j < 8; ++j) {
                float val = 0.0f;
                if (half == 0) {
                    if (inb)
                        val = X[(((size_t)(b * CINC + j) * SEQ + t) * HH + gy) * WW + gx];
                } else {
                    if (inb && t > 0)
                        val = __hip_atomic_load(
                            &out[(((size_t)(b * COUTC + j) * SEQ + (t - 1)) * HH + gy) * WW + gx],
                            __ATOMIC_RELAXED, __HIP_MEMORY_SCOPE_AGENT);
                }
                v[j] = val;
            }
            union { half8 h; float4 f; } uh, ul;
#pragma unroll
            for (int j = 0; j < 8; ++j) {
                _Float16 hi = (_Float16)v[j];
                uh.h[j] = hi;
                ul.h[j] = (_Float16)(v[j] - (float)hi);
            }
            *(float4*)&ldsH[(size_t)idx * 8] = uh.f;
            *(float4*)&ldsL[(size_t)idx * 8] = ul.f;
        }
        __syncthreads();

        // ---- MFMA: wave covers row ry, cols x0..x0+63 (2 N-tiles) ----
        floatx16 acc0, acc1;
#pragma unroll
        for (int r = 0; r < 16; ++r) { acc0[r] = 0.0f; acc1[r] = 0.0f; }

#pragma unroll
        for (int tap = 0; tap < TAPS; ++tap) {
            int ky = tap / 3, kx = tap % 3;
            int row = ry + ky;
            int base0 = ((lh * ROWS + row) * COLS + (x0 + lg + kx)) * 8;
            int base1 = base0 + 32 * 8;
            half8 bh0 = *(const half8*)&ldsH[base0];
            half8 bl0 = *(const half8*)&ldsL[base0];
            half8 bh1 = *(const half8*)&ldsH[base1];
            half8 bl1 = *(const half8*)&ldsL[base1];
            acc0 = __builtin_amdgcn_mfma_f32_32x32x16_f16(wfrag[tap], bh0, acc0, 0, 0, 0);
            acc1 = __builtin_amdgcn_mfma_f32_32x32x16_f16(wfrag[tap], bh1, acc1, 0, 0, 0);
            acc0 = __builtin_amdgcn_mfma_f32_32x32x16_f16(wfrag[tap], bl0, acc0, 0, 0, 0);
            acc1 = __builtin_amdgcn_mfma_f32_32x32x16_f16(wfrag[tap], bl1, acc1, 0, 0, 0);
        }
        __syncthreads();   // all waves' LDS reads done before epilogue h-writes

        // ---- epilogue: gates, c update, out store (sc1), h(t) -> next LDS ----
#pragma unroll
        for (int tl = 0; tl < 2; ++tl) {
            floatx16 A = tl ? acc1 : acc0;
            int px = x0 + tl * 32 + lg;
            half4 hh, hl;
#pragma unroll
            for (int r = 0; r < 4; ++r) {
                int oc = r + 4 * lh;
                float zi = A[r]      + bi[r];
                float zf = A[4 + r]  + bf4[r];
                float zg = A[8 + r]  + bg[r];
                float zo = A[12 + r] + bo[r];
                float cp = creg[tl * 4 + r];
                float cn = sigmoidf_(zf) * cp + sigmoidf_(zi) * tanhf_(zg);
                creg[tl * 4 + r] = cn;
                float hval = sigmoidf_(zo) * tanhf_(cn);
                __hip_atomic_store(
                    &out[(((size_t)(b * COUTC + oc) * SEQ + t) * HH + y) * WW + px],
                    hval, __ATOMIC_RELAXED, __HIP_MEMORY_SCOPE_AGENT);
                _Float16 hi = (_Float16)hval;
                hh[r] = hi;
                hl[r] = (_Float16)(hval - (float)hi);
            }
            // h(t) into next step's LDS window (half=1, row=1+ry, col=px+1)
            int hbase = (((1 * ROWS) + 1 + ry) * COLS + (px + 1)) * 8 + 4 * lh;
            *(half4*)&ldsH[hbase] = hh;
            *(half4*)&ldsL[hbase] = hl;
        }

        __syncthreads();   // implicit vmcnt(0) drain: all out stores globally visible
        if (tid == 0 && t + 1 < SEQ)
            __hip_atomic_fetch_add(&flags[blk], 1u,
                                   __ATOMIC_RELAXED, __HIP_MEMORY_SCOPE_AGENT);
    }
}

// ---------------------------------------------------------------------------
// Fallback path (proven baseline): one kernel per step, c-state in workspace.
// ---------------------------------------------------------------------------
__global__ __launch_bounds__(256, 4) void step_kernel(
    const float* __restrict__ X,
    const _Float16* __restrict__ Wf,
    const float* __restrict__ bc,
    float* __restrict__ out,
    float* __restrict__ c,
    int t)
{
    __shared__ __align__(16) _Float16 ldsH[2 * ROWS * COLS * 8];
    __shared__ __align__(16) _Float16 ldsL[2 * ROWS * COLS * 8];

    const int tid = threadIdx.x;
    const int b   = blockIdx.x >> 6;
    const int y0  = (blockIdx.x & 63) * 2;

    for (int idx = tid; idx < 2 * ROWS * COLS; idx += 256) {
        int col  = idx % COLS;
        int tmp  = idx / COLS;
        int half = tmp >> 2;
        int row  = tmp & 3;
        int gy = y0 + row - 1;
        int gx = col - 1;
        bool inb = ((unsigned)gy < HH) && ((unsigned)gx < WW);
        float v[8];
#pragma unroll
        for (int j = 0; j < 8; ++j) {
            int ch = half * 8 + j;
            float val = 0.0f;
            if (inb) {
                if (ch < CINC)
                    val = X[(((size_t)(b * CINC + ch) * SEQ + t) * HH + gy) * WW + gx];
                else if (t > 0)
                    val = out[(((size_t)(b * COUTC + (ch - 8)) * SEQ + (t - 1)) * HH + gy) * WW + gx];
            }
            v[j] = val;
        }
        union { half8 h; float4 f; } uh, ul;
#pragma unroll
        for (int j = 0; j < 8; ++j) {
            _Float16 hi = (_Float16)v[j];
            uh.h[j] = hi;
            ul.h[j] = (_Float16)(v[j] - (float)hi);
        }
        *(float4*)&ldsH[(size_t)idx * 8] = uh.f;
        *(float4*)&ldsL[(size_t)idx * 8] = ul.f;
    }

    const int lane = tid & 63;
    const int w    = tid >> 6;
    const int lg   = lane & 31;
    const int lh   = lane >> 5;

    half8 wfrag[TAPS];
#pragma unroll
    for (int tap = 0; tap < TAPS; ++tap)
        wfrag[tap] = *(const half8*)&Wf[((tap * NG + lg) * 2 + lh) * 8];

    __syncthreads();

    const int ry = w >> 1;
    const int x0 = (w & 1) * 64;

    floatx16 acc0, acc1;
#pragma unroll
    for (int r = 0; r < 16; ++r) { acc0[r] = 0.0f; acc1[r] = 0.0f; }

#pragma unroll
    for (int tap = 0; tap < TAPS; ++tap) {
        int ky = tap / 3, kx = tap % 3;
        int row = ry + ky;
        int base0 = ((lh * ROWS + row) * COLS + (x0 + lg + kx)) * 8;
        int base1 = base0 + 32 * 8;
        half8 bh0 = *(const half8*)&ldsH[base0];
        half8 bl0 = *(const half8*)&ldsL[base0];
        half8 bh1 = *(const half8*)&ldsH[base1];
        half8 bl1 = *(const half8*)&ldsL[base1];
        acc0 = __builtin_amdgcn_mfma_f32_32x32x16_f16(wfrag[tap], bh0, acc0, 0, 0, 0);
        acc1 = __builtin_amdgcn_mfma_f32_32x32x16_f16(wfrag[tap], bh1, acc1, 0, 0, 0);
        acc0 = __builtin_amdgcn_mfma_f32_32x32x16_f16(wfrag[tap], bl0, acc0, 0, 0, 0);
        acc1 = __builtin_amdgcn_mfma_f32_32x32x16_f16(wfrag[tap], bl1, acc1, 0, 0, 0);
    }

    const int y = y0 + ry;
#pragma unroll
    for (int tl = 0; tl < 2; ++tl) {
        floatx16 A = tl ? acc1 : acc0;
        int px = x0 + tl * 32 + lg;
#pragma unroll
        for (int r = 0; r < 4; ++r) {
            int oc = r + 4 * lh;
            float zi = A[r]      + bc[oc];
            float zf = A[4 + r]  + bc[oc + 8];
            float zg = A[8 + r]  + bc[oc + 16];
            float zo = A[12 + r] + bc[oc + 24];
            size_t ci = ((size_t)(b * COUTC + oc) * HH + y) * WW + px;
            float cp = (t > 0) ? c[ci] : 0.0f;
            float cn = sigmoidf_(zf) * cp + sigmoidf_(zi) * tanhf_(zg);
            c[ci] = cn;
            out[(((size_t)(b * COUTC + oc) * SEQ + t) * HH + y) * WW + px]
                = sigmoidf_(zo) * tanhf_(cn);
        }
    }
}

extern "C" void kernel_launch(void* const* d_in, const int* in_sizes, int n_in,
                              void* d_out, int out_size, void* d_ws, size_t ws_size,
                              hipStream_t stream) {
    const float* X  = (const float*)d_in[0];
    const float* Wc = (const float*)d_in[1];
    const float* bc = (const float*)d_in[2];
    float* out = (float*)d_out;

    _Float16* Wf    = (_Float16*)d_ws;                        // 9216 B
    unsigned* flags = (unsigned*)((char*)d_ws + 12288);       // 4096 B

    prep_weights<<<18, 256, 0, stream>>>(Wc, Wf, flags);

    void* args[] = { (void*)&X, (void*)&Wf, (void*)&bc, (void*)&out, (void*)&flags };
    hipError_t err = hipLaunchCooperativeKernel((const void*)lstm_fused,
                                                dim3(16 * 64), dim3(256),
                                                args, 0, stream);
    if (err != hipSuccess) {
        // fallback: proven per-step path with c-state in workspace
        float* c = (float*)((char*)d_ws + 16384);
        for (int t = 0; t < SEQ; ++t) {
            step_kernel<<<16 * 64, 256, 0, stream>>>(X, Wf, bc, out, c, t);
        }
    }
}